// Round 4
// baseline (1884.070 us; speedup 1.0000x reference)
//
#include <hip/hip_runtime.h>
#include <stdint.h>

#define B_ 16
#define N_ 4096
#define NPOINT_ 1024
#define NSAMPLE_ 32
#define PPB 32768            // NPOINT_*NSAMPLE_
#define PTOT 524288          // B_*PPB
#define EPS_ 1e-5f

typedef float v2f __attribute__((ext_vector_type(2)));

// ---------- bf16 helpers ----------
__device__ __forceinline__ float bf2f(unsigned short h) {
    unsigned int u = ((unsigned int)h) << 16;
    float f; __builtin_memcpy(&f, &u, 4); return f;
}
__device__ __forceinline__ unsigned short f2bf(float f) {
    unsigned int u; __builtin_memcpy(&u, &f, 4);
    u = (u + 0x7fffu + ((u >> 16) & 1u)) >> 16;   // RNE
    return (unsigned short)u;
}

// ---------- prep: zero G3/s3, transpose w1,w2 ----------
__global__ __launch_bounds__(256) void prep_kernel(const float* __restrict__ w1,
                                                   const float* __restrict__ w2,
                                                   float* __restrict__ w1t,
                                                   float* __restrict__ w2t,
                                                   float* __restrict__ g3s3) {
    int i = blockIdx.x * 256 + threadIdx.x;   // 32 blocks -> 8192
    if (i < 4160) g3s3[i] = 0.f;
    if (i < 4096) { int o = i >> 6, c = i & 63; w1t[c * 64 + o] = w1[i]; }
    if (i < 8192) { int o = i >> 6, c = i & 63; w2t[c * 128 + o] = w2[i]; }
}

// ---------- FPS ----------
// R18: TWO batches per block (8 blocks x 512 thr, ~104 KB LDS of the 160 KB/CU).
// R16/R17 established the iteration is ~2/3 serial latency (DPP chain, key
// write/read round trip, barrier, uniform center gather). The 16 chains are
// independent, so run two per block in lockstep: chain B's distance issue
// hides chain A's LDS/DPP latency and the per-iteration barrier + broadcast
// round trips are paid once for two batches. Per-batch math is bit-identical
// to R17 (same pk distance ops, same DPP reduce, same per-batch key tree,
// disjoint index sets) -> identical selection.
#define DPP_U64_MAX(ctrl)                                                          \
    {                                                                              \
        unsigned int nh = (unsigned int)__builtin_amdgcn_update_dpp(               \
            (int)bh, (int)bh, ctrl, 0xF, 0xF, false);                              \
        unsigned int nl = (unsigned int)__builtin_amdgcn_update_dpp(               \
            (int)bl, (int)bl, ctrl, 0xF, 0xF, false);                              \
        unsigned long long nk = ((unsigned long long)nh << 32) | nl;               \
        unsigned long long bk = ((unsigned long long)bh << 32) | bl;               \
        if (nk > bk) { bh = nh; bl = nl; }                                         \
    }

__device__ __forceinline__ unsigned long long wave_argmax_key(float bv, int bi) {
    unsigned int bh; __builtin_memcpy(&bh, &bv, 4);   // dist >= 0 -> monotone bits
    unsigned int bl = ~(unsigned int)bi;              // larger ~idx == smaller idx
    DPP_U64_MAX(0x111)   // row_shr:1
    DPP_U64_MAX(0x112)   // row_shr:2
    DPP_U64_MAX(0x114)   // row_shr:4
    DPP_U64_MAX(0x118)   // row_shr:8
    DPP_U64_MAX(0x142)   // row_bcast:15
    DPP_U64_MAX(0x143)   // row_bcast:31
    return ((unsigned long long)bh << 32) | bl;
}

// distance + local argmax over 8 points (4 v2f pairs), ascending index order:
// pair j covers (tid + j*1024, tid + j*1024 + 512); strict '>' keeps first.
#define DIST_ARGMAX(PX, PY, PZ, MD, CX, CY, CZ, BV, BI)                            \
    {                                                                              \
        v2f c2x; c2x[0] = (CX); c2x[1] = (CX);                                     \
        v2f c2y; c2y[0] = (CY); c2y[1] = (CY);                                     \
        v2f c2z; c2z[0] = (CZ); c2z[1] = (CZ);                                     \
        _Pragma("unroll")                                                          \
        for (int j = 0; j < 4; ++j) {                                              \
            v2f dx = PX[j] - c2x;                                                  \
            v2f dy = PY[j] - c2y;                                                  \
            v2f dz = PZ[j] - c2z;                                                  \
            v2f t0 = dx * dx;                                                      \
            v2f t1 = __builtin_elementwise_fma(dy, dy, t0);                        \
            v2f d2 = __builtin_elementwise_fma(dz, dz, t1);                        \
            v2f m  = __builtin_elementwise_min(MD[j], d2);                         \
            MD[j] = m;                                                             \
            bool g = m[1] > m[0];                                                  \
            float mloc = g ? m[1] : m[0];                                          \
            int iloc = (tid + j * 1024) + (g ? 512 : 0);                           \
            if (j == 0) { BV = mloc; BI = iloc; }                                  \
            else if (mloc > BV) { BV = mloc; BI = iloc; }                          \
        }                                                                          \
    }

// max tree over 8 per-wave keys (no cross-wave ties: disjoint idx sets)
#define TREE8(RED, CUR)                                                            \
    {                                                                              \
        const ulonglong2* rp = (const ulonglong2*)&RED[t & 1][0];                  \
        ulonglong2 r0 = rp[0], r1 = rp[1], r2 = rp[2], r3 = rp[3];                 \
        unsigned long long a0 = (r0.x > r0.y) ? r0.x : r0.y;                       \
        unsigned long long a1 = (r1.x > r1.y) ? r1.x : r1.y;                       \
        unsigned long long a2 = (r2.x > r2.y) ? r2.x : r2.y;                       \
        unsigned long long a3 = (r3.x > r3.y) ? r3.x : r3.y;                       \
        unsigned long long b0 = (a0 > a1) ? a0 : a1;                               \
        unsigned long long b1 = (a2 > a3) ? a2 : a3;                               \
        unsigned long long mm = (b0 > b1) ? b0 : b1;                               \
        CUR = (int)(~(unsigned int)mm) & (N_ - 1);                                 \
    }

__global__ __launch_bounds__(512) void fps_kernel(const float* __restrict__ xyz,
                                                  float* __restrict__ out0) {
    const int bA = blockIdx.x * 2, bB = bA + 1;
    const int tid = threadIdx.x;
    const int lane = tid & 63, wid = tid >> 6;   // wid 0..7
    __shared__ float sxA[N_], syA[N_], szA[N_];
    __shared__ float sxB[N_], syB[N_], szB[N_];
    __shared__ __align__(16) unsigned long long redA[2][8];
    __shared__ __align__(16) unsigned long long redB[2][8];
    __shared__ int sidxA[NPOINT_], sidxB[NPOINT_];
    const float* xbA = xyz + (size_t)bA * 3 * N_;
    const float* xbB = xyz + (size_t)bB * 3 * N_;
    for (int p = tid; p < N_; p += 512) {
        sxA[p] = xbA[p]; syA[p] = xbA[N_ + p]; szA[p] = xbA[2 * N_ + p];
        sxB[p] = xbB[p]; syB[p] = xbB[N_ + p]; szB[p] = xbB[2 * N_ + p];
    }
    __syncthreads();
    v2f pxA[4], pyA[4], pzA[4], mdA[4];
    v2f pxB[4], pyB[4], pzB[4], mdB[4];
#pragma unroll
    for (int j = 0; j < 4; ++j) {
        int p = tid + j * 1024;
        pxA[j][0] = sxA[p];  pxA[j][1] = sxA[p + 512];
        pyA[j][0] = syA[p];  pyA[j][1] = syA[p + 512];
        pzA[j][0] = szA[p];  pzA[j][1] = szA[p + 512];
        pxB[j][0] = sxB[p];  pxB[j][1] = sxB[p + 512];
        pyB[j][0] = syB[p];  pyB[j][1] = syB[p + 512];
        pzB[j][0] = szB[p];  pzB[j][1] = szB[p + 512];
        mdA[j][0] = 1e10f;   mdA[j][1] = 1e10f;
        mdB[j][0] = 1e10f;   mdB[j][1] = 1e10f;
    }
    int curA = 0, curB = 0;
    for (int t = 0; t < NPOINT_; ++t) {
        if (tid == 0) { sidxA[t] = curA; sidxB[t] = curB; }   // LDS only
        // issue both centers' uniform gathers together (latencies overlap)
        float cxA = sxA[curA], cyA = syA[curA], czA = szA[curA];
        float cxB = sxB[curB], cyB = syB[curB], czB = szB[curB];
        float bvA; int biA;
        float bvB; int biB;
        DIST_ARGMAX(pxA, pyA, pzA, mdA, cxA, cyA, czA, bvA, biA)
        DIST_ARGMAX(pxB, pyB, pzB, mdB, cxB, cyB, czB, bvB, biB)
        unsigned long long keyA = wave_argmax_key(bvA, biA);
        unsigned long long keyB = wave_argmax_key(bvB, biB);
        if (lane == 63) {
            redA[t & 1][wid] = keyA;
            redB[t & 1][wid] = keyB;
        }
        __syncthreads();
        TREE8(redA, curA)
        TREE8(redB, curB)
    }
    __syncthreads();
    // coalesced epilogue: gather centers from LDS, store once
    for (int t = tid; t < NPOINT_; t += 512) {
        int ixA = sidxA[t];
        out0[(size_t)bA * 3 * NPOINT_ + t]               = sxA[ixA];
        out0[(size_t)bA * 3 * NPOINT_ + NPOINT_ + t]     = syA[ixA];
        out0[(size_t)bA * 3 * NPOINT_ + 2 * NPOINT_ + t] = szA[ixA];
        int ixB = sidxB[t];
        out0[(size_t)bB * 3 * NPOINT_ + t]               = sxB[ixB];
        out0[(size_t)bB * 3 * NPOINT_ + NPOINT_ + t]     = syB[ixB];
        out0[(size_t)bB * 3 * NPOINT_ + 2 * NPOINT_ + t] = szB[ixB];
    }
}

// ---------- ball query: fp32 FMA-contracted (VERIFIED R10) ----------
__global__ __launch_bounds__(256) void ball_kernel(const float* __restrict__ xyz,
                                                   const float* __restrict__ out0,
                                                   int* __restrict__ ball_idx) {
    int gid  = (blockIdx.x * 256 + threadIdx.x) >> 6;
    int lane = threadIdx.x & 63;
    int b = gid >> 10, s = gid & 1023;
    const float* xb = xyz + (size_t)b * 3 * N_;
    float qx = out0[(size_t)b * 3 * NPOINT_ + s];
    float qy = out0[(size_t)b * 3 * NPOINT_ + NPOINT_ + s];
    float qz = out0[(size_t)b * 3 * NPOINT_ + 2 * NPOINT_ + s];
    float qs = __builtin_fmaf(qz, qz, __builtin_fmaf(qy, qy, __fmul_rn(qx, qx)));
    int cnt = 0, first = 0;
    int* outp = ball_idx + (size_t)gid * NSAMPLE_;
    for (int n0 = 0; n0 < N_; n0 += 64) {
        int n = n0 + lane;
        float px = xb[n], py = xb[N_ + n], pz = xb[2 * N_ + n];
        float dot = __builtin_fmaf(qz, pz, __builtin_fmaf(qy, py, __fmul_rn(qx, px)));
        float ps  = __builtin_fmaf(pz, pz, __builtin_fmaf(py, py, __fmul_rn(px, px)));
        float d   = __fadd_rn(__builtin_fmaf(-2.f, dot, qs), ps);
        bool ok = !(d > 0.04f);
        unsigned long long m = __ballot(ok);
        if (m) {
            if (cnt == 0) first = n0 + (__ffsll((unsigned long long)m) - 1);
            if (ok) {
                int r = __popcll(m & ((1ull << lane) - 1ull));
                int pos = cnt + r;
                if (pos < NSAMPLE_) outp[pos] = n;
            }
            cnt += __popcll(m);
            if (cnt >= NSAMPLE_) break;
        }
    }
    if (cnt < NSAMPLE_) {
        for (int pos = cnt + lane; pos < NSAMPLE_; pos += 64) outp[pos] = first;
    }
}

// ---------- conv1 stats: per-block partial sums of y1, y1^2 ----------
__global__ __launch_bounds__(256) void conv1_stats_kernel(const float* __restrict__ xyz,
                                                          const float* __restrict__ pts,
                                                          const float* __restrict__ out0,
                                                          const int* __restrict__ ball_idx,
                                                          const float* __restrict__ w0,
                                                          const float* __restrict__ b0,
                                                          float* __restrict__ partial1) {
    __shared__ float sw[448];
    __shared__ float lsum[256], lsq[256];
    int tid = threadIdx.x;
    int lane = tid & 63, wid = tid >> 6;
    for (int i = tid; i < 448; i += 256) sw[i] = (i < 384) ? w0[i] : b0[i - 384];
    __syncthreads();
    int p = blockIdx.x * 256 + tid;
    int b = p >> 15, s = (p & 32767) >> 5;
    int gi = ball_idx[p];
    const float* xb = xyz + (size_t)b * 3 * N_;
    const float* pb = pts + (size_t)b * 3 * N_;
    float x0 = xb[gi]          - out0[(size_t)b * 3 * NPOINT_ + s];
    float x1 = xb[N_ + gi]     - out0[(size_t)b * 3 * NPOINT_ + NPOINT_ + s];
    float x2 = xb[2 * N_ + gi] - out0[(size_t)b * 3 * NPOINT_ + 2 * NPOINT_ + s];
    float x3 = pb[gi], x4 = pb[N_ + gi], x5 = pb[2 * N_ + gi];
#pragma unroll
    for (int o = 0; o < 64; ++o) {
        float a = sw[384 + o];
        a += sw[o * 6 + 0] * x0; a += sw[o * 6 + 1] * x1; a += sw[o * 6 + 2] * x2;
        a += sw[o * 6 + 3] * x3; a += sw[o * 6 + 4] * x4; a += sw[o * 6 + 5] * x5;
        float v = a, v2 = a * a;
#pragma unroll
        for (int off = 32; off >= 1; off >>= 1) {
            v  += __shfl_down(v, off);
            v2 += __shfl_down(v2, off);
        }
        if (lane == 0) { lsum[wid * 64 + o] = v; lsq[wid * 64 + o] = v2; }
    }
    __syncthreads();
    if (tid < 64)
        partial1[(size_t)blockIdx.x * 128 + tid] =
            lsum[tid] + lsum[64 + tid] + lsum[128 + tid] + lsum[192 + tid];
    else if (tid < 128) {
        int c = tid - 64;
        partial1[(size_t)blockIdx.x * 128 + tid] =
            lsq[c] + lsq[64 + c] + lsq[128 + c] + lsq[192 + c];
    }
}

// ---------- reduce partials -> scale/shift ----------
__global__ __launch_bounds__(256) void reduce_finalize_kernel(const float* __restrict__ partials,
                                                              int nblocks,
                                                              const float* __restrict__ gamma,
                                                              const float* __restrict__ beta,
                                                              float* __restrict__ scale,
                                                              float* __restrict__ shift) {
    int c = blockIdx.x;
    int tid = threadIdx.x, lane = tid & 63, wid = tid >> 6;
    float s1 = 0.f, s2 = 0.f;
    for (int i = tid; i < nblocks; i += 256) {
        s1 += partials[(size_t)i * 128 + c];
        s2 += partials[(size_t)i * 128 + 64 + c];
    }
#pragma unroll
    for (int off = 32; off >= 1; off >>= 1) {
        s1 += __shfl_down(s1, off);
        s2 += __shfl_down(s2, off);
    }
    __shared__ float r1[4], r2[4];
    if (lane == 0) { r1[wid] = s1; r2[wid] = s2; }
    __syncthreads();
    if (tid == 0) {
        float S1 = r1[0] + r1[1] + r1[2] + r1[3];
        float S2 = r2[0] + r2[1] + r2[2] + r2[3];
        const float inv = 1.f / (float)PTOT;
        float m = S1 * inv;
        float v = S2 * inv - m * m;
        float sc = gamma[c] / sqrtf(v + EPS_);
        scale[c] = sc;
        shift[c] = beta[c] - m * sc;
    }
}

// ---------- conv2 fused: recompute conv1+bn1+relu, 64x64 GEMM, stats, store y2 bf16 ----------
__global__ __launch_bounds__(256) void conv2_fused_kernel(const float* __restrict__ xyz,
                                                          const float* __restrict__ pts,
                                                          const float* __restrict__ out0,
                                                          const int* __restrict__ ball_idx,
                                                          const float* __restrict__ w0,
                                                          const float* __restrict__ b0,
                                                          const float* __restrict__ w1t,  // [64c][64o]
                                                          const float* __restrict__ b1,
                                                          const float* __restrict__ scale1,
                                                          const float* __restrict__ shift1,
                                                          unsigned short* __restrict__ y2,
                                                          float* __restrict__ partial2) {
    __shared__ float sw0[448];
    __shared__ float x1s[6 * 64];
    __shared__ float Xs[64 * 64];
    __shared__ float Ws[64 * 64];
    __shared__ float ssc[64], ssh[64], sb1[64];
    __shared__ float lsum[64], lsq[64];
    int tid = threadIdx.x;
    int p0 = blockIdx.x * 64;
    for (int i = tid; i < 448; i += 256) sw0[i] = (i < 384) ? w0[i] : b0[i - 384];
    for (int i = tid; i < 4096; i += 256) Ws[i] = w1t[i];
    if (tid < 64) { ssc[tid] = scale1[tid]; ssh[tid] = shift1[tid]; sb1[tid] = b1[tid]; }
    if (tid < 64) {
        int p = p0 + tid;
        int b = p >> 15, s = (p & 32767) >> 5;
        int gi = ball_idx[p];
        const float* xb = xyz + (size_t)b * 3 * N_;
        const float* pb = pts + (size_t)b * 3 * N_;
        x1s[0 * 64 + tid] = xb[gi]          - out0[(size_t)b * 3 * NPOINT_ + s];
        x1s[1 * 64 + tid] = xb[N_ + gi]     - out0[(size_t)b * 3 * NPOINT_ + NPOINT_ + s];
        x1s[2 * 64 + tid] = xb[2 * N_ + gi] - out0[(size_t)b * 3 * NPOINT_ + 2 * NPOINT_ + s];
        x1s[3 * 64 + tid] = pb[gi];
        x1s[4 * 64 + tid] = pb[N_ + gi];
        x1s[5 * 64 + tid] = pb[2 * N_ + gi];
    }
    __syncthreads();
    for (int i = tid; i < 4096; i += 256) {
        int c = i >> 6, p = i & 63;
        float a = sw0[384 + c];
        a += sw0[c * 6 + 0] * x1s[p];
        a += sw0[c * 6 + 1] * x1s[64 + p];
        a += sw0[c * 6 + 2] * x1s[128 + p];
        a += sw0[c * 6 + 3] * x1s[192 + p];
        a += sw0[c * 6 + 4] * x1s[256 + p];
        a += sw0[c * 6 + 5] * x1s[320 + p];
        Xs[i] = fmaxf(a * ssc[c] + ssh[c], 0.f);
    }
    __syncthreads();
    int pt = tid & 15, ot = tid >> 4;
    float acc[16];
#pragma unroll
    for (int i = 0; i < 4; ++i) {
        float bv = sb1[ot * 4 + i];
        acc[i * 4 + 0] = bv; acc[i * 4 + 1] = bv; acc[i * 4 + 2] = bv; acc[i * 4 + 3] = bv;
    }
#pragma unroll 4
    for (int c = 0; c < 64; ++c) {
        float4 xv = *(const float4*)&Xs[c * 64 + pt * 4];
        float4 wv = *(const float4*)&Ws[c * 64 + ot * 4];
        acc[0]  += wv.x * xv.x; acc[1]  += wv.x * xv.y; acc[2]  += wv.x * xv.z; acc[3]  += wv.x * xv.w;
        acc[4]  += wv.y * xv.x; acc[5]  += wv.y * xv.y; acc[6]  += wv.y * xv.z; acc[7]  += wv.y * xv.w;
        acc[8]  += wv.z * xv.x; acc[9]  += wv.z * xv.y; acc[10] += wv.z * xv.z; acc[11] += wv.z * xv.w;
        acc[12] += wv.w * xv.x; acc[13] += wv.w * xv.y; acc[14] += wv.w * xv.z; acc[15] += wv.w * xv.w;
    }
    float sA[4], sQ[4];
#pragma unroll
    for (int i = 0; i < 4; ++i) {
        int o = ot * 4 + i;
        ushort4 u;
        u.x = f2bf(acc[i * 4 + 0]); u.y = f2bf(acc[i * 4 + 1]);
        u.z = f2bf(acc[i * 4 + 2]); u.w = f2bf(acc[i * 4 + 3]);
        *(ushort4*)(y2 + (size_t)o * PTOT + p0 + pt * 4) = u;
        sA[i] = acc[i * 4] + acc[i * 4 + 1] + acc[i * 4 + 2] + acc[i * 4 + 3];
        sQ[i] = acc[i * 4] * acc[i * 4] + acc[i * 4 + 1] * acc[i * 4 + 1]
              + acc[i * 4 + 2] * acc[i * 4 + 2] + acc[i * 4 + 3] * acc[i * 4 + 3];
    }
#pragma unroll
    for (int off = 8; off >= 1; off >>= 1) {
#pragma unroll
        for (int i = 0; i < 4; ++i) {
            sA[i] += __shfl_down(sA[i], off);
            sQ[i] += __shfl_down(sQ[i], off);
        }
    }
    if ((tid & 15) == 0) {
#pragma unroll
        for (int i = 0; i < 4; ++i) { lsum[ot * 4 + i] = sA[i]; lsq[ot * 4 + i] = sQ[i]; }
    }
    __syncthreads();
    if (tid < 64) partial2[(size_t)blockIdx.x * 128 + tid] = lsum[tid];
    else if (tid < 128) partial2[(size_t)blockIdx.x * 128 + tid] = lsq[tid - 64];
}

// ---------- gram3: G3 = sum x3 x3^T, s3 = sum x3, x3 = relu(affine2(y2)) ----------
__global__ __launch_bounds__(256) void gram3_kernel(const unsigned short* __restrict__ y2,
                                                    const float* __restrict__ scale2,
                                                    const float* __restrict__ shift2,
                                                    float* __restrict__ G3,
                                                    float* __restrict__ s3) {
    __shared__ __align__(16) float Xst[64 * 68];   // [p][c], stride 68
    __shared__ float ssc[64], ssh[64];
    int tid = threadIdx.x;
    if (tid < 64) { ssc[tid] = scale2[tid]; ssh[tid] = shift2[tid]; }
    int r = tid >> 4, q = tid & 15;
    float g[16];
#pragma unroll
    for (int i = 0; i < 16; ++i) g[i] = 0.f;
    float srow[4] = {0.f, 0.f, 0.f, 0.f};
    int pbase = blockIdx.x * 2048;
    for (int tile = 0; tile < 32; ++tile) {
        __syncthreads();
        int pb = pbase + tile * 64;
        for (int i = tid * 4; i < 4096; i += 1024) {
            int c = i >> 6, p4 = i & 63;
            ushort4 u = *(const ushort4*)(y2 + (size_t)c * PTOT + pb + p4);
            float sc = ssc[c], sh = ssh[c];
            Xst[(p4 + 0) * 68 + c] = fmaxf(bf2f(u.x) * sc + sh, 0.f);
            Xst[(p4 + 1) * 68 + c] = fmaxf(bf2f(u.y) * sc + sh, 0.f);
            Xst[(p4 + 2) * 68 + c] = fmaxf(bf2f(u.z) * sc + sh, 0.f);
            Xst[(p4 + 3) * 68 + c] = fmaxf(bf2f(u.w) * sc + sh, 0.f);
        }
        __syncthreads();
#pragma unroll 4
        for (int p = 0; p < 64; ++p) {
            float4 av = *(const float4*)&Xst[p * 68 + r * 4];
            float4 bv = *(const float4*)&Xst[p * 68 + q * 4];
            g[0]  += av.x * bv.x; g[1]  += av.x * bv.y; g[2]  += av.x * bv.z; g[3]  += av.x * bv.w;
            g[4]  += av.y * bv.x; g[5]  += av.y * bv.y; g[6]  += av.y * bv.z; g[7]  += av.y * bv.w;
            g[8]  += av.z * bv.x; g[9]  += av.z * bv.y; g[10] += av.z * bv.z; g[11] += av.z * bv.w;
            g[12] += av.w * bv.x; g[13] += av.w * bv.y; g[14] += av.w * bv.z; g[15] += av.w * bv.w;
            if (q == 0) { srow[0] += av.x; srow[1] += av.y; srow[2] += av.z; srow[3] += av.w; }
        }
    }
#pragma unroll
    for (int i = 0; i < 4; ++i)
#pragma unroll
        for (int j = 0; j < 4; ++j)
            atomicAdd(&G3[(r * 4 + i) * 64 + q * 4 + j], g[i * 4 + j]);
    if (q == 0) {
#pragma unroll
        for (int i = 0; i < 4; ++i) atomicAdd(&s3[r * 4 + i], srow[i]);
    }
}

// ---------- finalize3: Gram -> scale3/shift3 ----------
__global__ __launch_bounds__(64) void finalize3_kernel(const float* __restrict__ G3,
                                                       const float* __restrict__ s3,
                                                       const float* __restrict__ w2,
                                                       const float* __restrict__ b2,
                                                       const float* __restrict__ gamma,
                                                       const float* __restrict__ beta,
                                                       float* __restrict__ scale,
                                                       float* __restrict__ shift) {
    int o = blockIdx.x * 64 + threadIdx.x;
    const float* wr = w2 + o * 64;
    double ws = 0.0;
    for (int c = 0; c < 64; ++c) ws += (double)wr[c] * (double)s3[c];
    double qf = 0.0;
    for (int i = 0; i < 64; ++i) {
        double ti = 0.0;
        for (int j = 0; j < 64; ++j) ti += (double)G3[i * 64 + j] * (double)wr[j];
        qf += (double)wr[i] * ti;
    }
    const double invP = 1.0 / (double)PTOT;
    double bb = (double)b2[o];
    double mean = ws * invP + bb;
    double ey2 = qf * invP + 2.0 * bb * (ws * invP) + bb * bb;
    double var = ey2 - mean * mean;
    float sc = gamma[o] / sqrtf((float)var + EPS_);
    scale[o] = sc;
    shift[o] = beta[o] - (float)mean * sc;
}

// ---------- conv3 + bn3 + relu + maxpool fused (tiled, bf16 y2 in) ----------
__global__ __launch_bounds__(256) void conv3_maxpool_kernel(const unsigned short* __restrict__ y2,
                                                            const float* __restrict__ w2t,  // [64c][128o]
                                                            const float* __restrict__ b2,
                                                            const float* __restrict__ scale2,
                                                            const float* __restrict__ shift2,
                                                            const float* __restrict__ scale3,
                                                            const float* __restrict__ shift3,
                                                            float* __restrict__ out1) {
    __shared__ float Xs[64 * 64];
    __shared__ float Ws[64 * 128];
    __shared__ float ssc2[64], ssh2[64];
    __shared__ float sb2[128], ssc3[128], ssh3[128];
    __shared__ float gmax[256];   // [2 groups][128 ch]
    int tid = threadIdx.x;
    int p0 = blockIdx.x * 64;
    if (tid < 64) { ssc2[tid] = scale2[tid]; ssh2[tid] = shift2[tid]; }
    for (int i = tid; i < 128; i += 256) { sb2[i] = b2[i]; ssc3[i] = scale3[i]; ssh3[i] = shift3[i]; }
    for (int i = tid; i < 8192; i += 256) Ws[i] = w2t[i];
    __syncthreads();
    for (int i = tid * 4; i < 4096; i += 1024) {
        int c = i >> 6, pp = i & 63;
        ushort4 u = *(const ushort4*)(y2 + (size_t)c * PTOT + p0 + pp);
        float sc = ssc2[c], sh = ssh2[c];
        float4 x;
        x.x = fmaxf(bf2f(u.x) * sc + sh, 0.f);
        x.y = fmaxf(bf2f(u.y) * sc + sh, 0.f);
        x.z = fmaxf(bf2f(u.z) * sc + sh, 0.f);
        x.w = fmaxf(bf2f(u.w) * sc + sh, 0.f);
        *(float4*)&Xs[i] = x;
    }
    int pt = tid & 15, ot = tid >> 4;
    float acc[32];
#pragma unroll
    for (int i = 0; i < 8; ++i) {
        float bv = sb2[ot * 8 + i];
        acc[i * 4 + 0] = bv; acc[i * 4 + 1] = bv; acc[i * 4 + 2] = bv; acc[i * 4 + 3] = bv;
    }
    __syncthreads();
#pragma unroll 4
    for (int c = 0; c < 64; ++c) {
        float4 xv = *(const float4*)&Xs[c * 64 + pt * 4];
#pragma unroll
        for (int i2 = 0; i2 < 2; ++i2) {
            float4 wv = *(const float4*)&Ws[c * 128 + ot * 8 + i2 * 4];
            float* a = &acc[i2 * 16];
            a[0]  += wv.x * xv.x; a[1]  += wv.x * xv.y; a[2]  += wv.x * xv.z; a[3]  += wv.x * xv.w;
            a[4]  += wv.y * xv.x; a[5]  += wv.y * xv.y; a[6]  += wv.y * xv.z; a[7]  += wv.y * xv.w;
            a[8]  += wv.z * xv.x; a[9]  += wv.z * xv.y; a[10] += wv.z * xv.z; a[11] += wv.z * xv.w;
            a[12] += wv.w * xv.x; a[13] += wv.w * xv.y; a[14] += wv.w * xv.z; a[15] += wv.w * xv.w;
        }
    }
    float mx[8];
#pragma unroll
    for (int i = 0; i < 8; ++i) {
        int o = ot * 8 + i;
        float sc = ssc3[o], sh = ssh3[o];
        float m = acc[i * 4 + 0] * sc + sh;
        m = fmaxf(m, acc[i * 4 + 1] * sc + sh);
        m = fmaxf(m, acc[i * 4 + 2] * sc + sh);
        m = fmaxf(m, acc[i * 4 + 3] * sc + sh);
        mx[i] = m;
    }
#pragma unroll
    for (int off = 4; off >= 1; off >>= 1)
#pragma unroll
        for (int i = 0; i < 8; ++i) mx[i] = fmaxf(mx[i], __shfl_down(mx[i], off));
    if ((pt & 7) == 0) {
        int gph = pt >> 3;
#pragma unroll
        for (int i = 0; i < 8; ++i) gmax[gph * 128 + ot * 8 + i] = fmaxf(mx[i], 0.f);
    }
    __syncthreads();
    int b = p0 >> 15, s0 = (p0 & 32767) >> 5;
    int o = tid >> 1, gph = tid & 1;
    out1[(size_t)b * 131072 + (size_t)o * 1024 + s0 + gph] = gmax[gph * 128 + o];
}

extern "C" void kernel_launch(void* const* d_in, const int* in_sizes, int n_in,
                              void* d_out, int out_size, void* d_ws, size_t ws_size,
                              hipStream_t stream) {
    (void)in_sizes; (void)n_in; (void)out_size; (void)ws_size;
    const float* xyz    = (const float*)d_in[0];
    const float* pts    = (const float*)d_in[1];
    const float* w0     = (const float*)d_in[2];
    const float* b0     = (const float*)d_in[3];
    const float* gamma0 = (const float*)d_in[4];
    const float* beta0  = (const float*)d_in[5];
    const float* w1     = (const float*)d_in[6];
    const float* b1     = (const float*)d_in[7];
    const float* gamma1 = (const float*)d_in[8];
    const float* beta1  = (const float*)d_in[9];
    const float* w2     = (const float*)d_in[10];
    const float* b2     = (const float*)d_in[11];
    const float* gamma2 = (const float*)d_in[12];
    const float* beta2  = (const float*)d_in[13];

    char* ws = (char*)d_ws;
    int*   ball_idx = (int*)(ws + 0);                       // 2 MB
    float* partial1 = (float*)(ws + 2097152);               // 1 MB (2048*128)
    float* partial2 = (float*)(ws + 3145728);               // 4 MB (8192*128)
    float* G3       = (float*)(ws + 7340032);               // 16 KB (+ s3 contiguous)
    float* s3       = (float*)(ws + 7356416);               // 256 B
    float* scsh     = (float*)(ws + 7357440);               // 2 KB
    float* w1t      = (float*)(ws + 7359488);               // 16 KB
    float* w2t      = (float*)(ws + 7375872);               // 32 KB
    unsigned short* y2 = (unsigned short*)(ws + 7408640);   // 64 MB -> total ~71.5 MB

    float* scale1 = scsh,       *shift1 = scsh + 64;
    float* scale2 = scsh + 128, *shift2 = scsh + 192;
    float* scale3 = scsh + 256, *shift3 = scsh + 384;

    float* out0 = (float*)d_out;                 // (B,3,NPOINT)
    float* out1 = out0 + B_ * 3 * NPOINT_;       // (B,128,NPOINT)

    hipLaunchKernelGGL(prep_kernel, dim3(32), dim3(256), 0, stream, w1, w2, w1t, w2t, G3);
    hipLaunchKernelGGL(fps_kernel, dim3(B_ / 2), dim3(512), 0, stream, xyz, out0);
    hipLaunchKernelGGL(ball_kernel, dim3(4096), dim3(256), 0, stream, xyz, out0, ball_idx);
    hipLaunchKernelGGL(conv1_stats_kernel, dim3(2048), dim3(256), 0, stream,
                       xyz, pts, out0, ball_idx, w0, b0, partial1);
    hipLaunchKernelGGL(reduce_finalize_kernel, dim3(64), dim3(256), 0, stream,
                       partial1, 2048, gamma0, beta0, scale1, shift1);
    hipLaunchKernelGGL(conv2_fused_kernel, dim3(8192), dim3(256), 0, stream,
                       xyz, pts, out0, ball_idx, w0, b0, w1t, b1, scale1, shift1, y2, partial2);
    hipLaunchKernelGGL(reduce_finalize_kernel, dim3(64), dim3(256), 0, stream,
                       partial2, 8192, gamma1, beta1, scale2, shift2);
    hipLaunchKernelGGL(gram3_kernel, dim3(256), dim3(256), 0, stream, y2, scale2, shift2, G3, s3);
    hipLaunchKernelGGL(finalize3_kernel, dim3(2), dim3(64), 0, stream,
                       G3, s3, w2, b2, gamma2, beta2, scale3, shift3);
    hipLaunchKernelGGL(conv3_maxpool_kernel, dim3(8192), dim3(256), 0, stream,
                       y2, w2t, b2, scale2, shift2, scale3, shift3, out1);
}

// Round 5
// 1305.597 us; speedup vs baseline: 1.4431x; 1.4431x over previous
//
#include <hip/hip_runtime.h>
#include <stdint.h>

#define B_ 16
#define N_ 4096
#define NPOINT_ 1024
#define NSAMPLE_ 32
#define PPB 32768            // NPOINT_*NSAMPLE_
#define PTOT 524288          // B_*PPB
#define EPS_ 1e-5f

typedef float v2f __attribute__((ext_vector_type(2)));

// ---------- bf16 helpers ----------
__device__ __forceinline__ float bf2f(unsigned short h) {
    unsigned int u = ((unsigned int)h) << 16;
    float f; __builtin_memcpy(&f, &u, 4); return f;
}
__device__ __forceinline__ unsigned short f2bf(float f) {
    unsigned int u; __builtin_memcpy(&u, &f, 4);
    u = (u + 0x7fffu + ((u >> 16) & 1u)) >> 16;   // RNE
    return (unsigned short)u;
}

// ---------- prep: zero G3/s3, transpose w1,w2 ----------
__global__ __launch_bounds__(256) void prep_kernel(const float* __restrict__ w1,
                                                   const float* __restrict__ w2,
                                                   float* __restrict__ w1t,
                                                   float* __restrict__ w2t,
                                                   float* __restrict__ g3s3) {
    int i = blockIdx.x * 256 + threadIdx.x;   // 32 blocks -> 8192
    if (i < 4160) g3s3[i] = 0.f;
    if (i < 4096) { int o = i >> 6, c = i & 63; w1t[c * 64 + o] = w1[i]; }
    if (i < 8192) { int o = i >> 6, c = i & 63; w2t[c * 128 + o] = w2[i]; }
}

// ---------- FPS ----------
// R19: revert to R17 shape (16 blocks x 512 thr; R18's two-batch stacking
// proved the iteration is VALU-ISSUE-bound at ~70-80% on active CUs:
// doubling per-wave work cost 1.84x). Cut issue on the argmax path:
//  (a) distance phase keeps ONLY md=min(md,d2) — no per-pair index tracking;
//  (b) wave reduce is a u32 VALUE max (dist>=0 -> monotone bits):
//      6x(dpp+v_max_u32) instead of the 30-instr u64 tie-break chain;
//  (c) index recovered by equality ballots against the broadcast wave max:
//      8x v_cmp_eq; the first-nonzero-slot + ctz pick is uniform -> SALU
//      (free when VALU-bound). Slot-order + ctz = smallest index among
//      ties, i.e. exact jnp.argmax first-match semantics; cross-wave ties
//      resolved by the unchanged (value,~idx) u64 key tree.
// Distance math bit-identical to R16/R17 -> identical selection.
#define DPP_U32_MAX(ctrl)                                                          \
    {                                                                              \
        unsigned int n = (unsigned int)__builtin_amdgcn_update_dpp(                \
            (int)mb, (int)mb, ctrl, 0xF, 0xF, false);                              \
        mb = (n > mb) ? n : mb;                                                    \
    }

// max tree over 8 per-wave keys; ties across waves resolved by ~idx low word
#define TREE8(RED, CUR)                                                            \
    {                                                                              \
        const ulonglong2* rp = (const ulonglong2*)&RED[t & 1][0];                  \
        ulonglong2 r0 = rp[0], r1 = rp[1], r2 = rp[2], r3 = rp[3];                 \
        unsigned long long a0 = (r0.x > r0.y) ? r0.x : r0.y;                       \
        unsigned long long a1 = (r1.x > r1.y) ? r1.x : r1.y;                       \
        unsigned long long a2 = (r2.x > r2.y) ? r2.x : r2.y;                       \
        unsigned long long a3 = (r3.x > r3.y) ? r3.x : r3.y;                       \
        unsigned long long b0 = (a0 > a1) ? a0 : a1;                               \
        unsigned long long b1 = (a2 > a3) ? a2 : a3;                               \
        unsigned long long mm = (b0 > b1) ? b0 : b1;                               \
        CUR = (int)(~(unsigned int)mm) & (N_ - 1);                                 \
    }

__global__ __launch_bounds__(512) void fps_kernel(const float* __restrict__ xyz,
                                                  float* __restrict__ out0) {
    const int b = blockIdx.x;
    const int tid = threadIdx.x;
    const int lane = tid & 63, wid = tid >> 6;   // wid 0..7
    __shared__ float sx[N_], sy[N_], sz[N_];
    __shared__ __align__(16) unsigned long long red[2][8];
    __shared__ int sidx[NPOINT_];
    const float* xb = xyz + (size_t)b * 3 * N_;
    for (int p = tid; p < N_; p += 512) {
        sx[p] = xb[p]; sy[p] = xb[N_ + p]; sz[p] = xb[2 * N_ + p];
    }
    __syncthreads();
    // slot s = j*2+k covers point index tid + s*512 (ascending in s)
    v2f px2[4], py2[4], pz2[4], md2[4];
#pragma unroll
    for (int j = 0; j < 4; ++j) {
        int p = tid + j * 1024;
        px2[j][0] = sx[p];       px2[j][1] = sx[p + 512];
        py2[j][0] = sy[p];       py2[j][1] = sy[p + 512];
        pz2[j][0] = sz[p];       pz2[j][1] = sz[p + 512];
        md2[j][0] = 1e10f;       md2[j][1] = 1e10f;
    }
    int cur = 0;
    for (int t = 0; t < NPOINT_; ++t) {
        if (tid == 0) sidx[t] = cur;           // LDS only — no vmcnt on the loop
        float cx = sx[cur], cy = sy[cur], cz = sz[cur];
        v2f c2x; c2x[0] = cx; c2x[1] = cx;
        v2f c2y; c2y[0] = cy; c2y[1] = cy;
        v2f c2z; c2z[0] = cz; c2z[1] = cz;
#pragma unroll
        for (int j = 0; j < 4; ++j) {
            // pk sub/mul/fma/min: per-element rounding identical to the
            // scalar __fmul_rn/__builtin_fmaf chain -> same selection
            v2f dx = px2[j] - c2x;
            v2f dy = py2[j] - c2y;
            v2f dz = pz2[j] - c2z;
            v2f t0 = dx * dx;
            v2f t1 = __builtin_elementwise_fma(dy, dy, t0);
            v2f d2 = __builtin_elementwise_fma(dz, dz, t1);
            md2[j] = __builtin_elementwise_min(md2[j], d2);
        }
        // lane-local max of the 8 running minima (value only)
        v2f m01 = __builtin_elementwise_max(md2[0], md2[1]);
        v2f m23 = __builtin_elementwise_max(md2[2], md2[3]);
        v2f mq  = __builtin_elementwise_max(m01, m23);
        float lm = fmaxf(mq[0], mq[1]);
        unsigned int mb; __builtin_memcpy(&mb, &lm, 4);   // >=0 -> monotone bits
        DPP_U32_MAX(0x111)   // row_shr:1
        DPP_U32_MAX(0x112)   // row_shr:2
        DPP_U32_MAX(0x114)   // row_shr:4
        DPP_U32_MAX(0x118)   // row_shr:8
        DPP_U32_MAX(0x142)   // row_bcast:15
        DPP_U32_MAX(0x143)   // row_bcast:31
        unsigned int Mw = (unsigned int)__builtin_amdgcn_readlane((int)mb, 63);
        // equality ballots in slot order; results are wave-uniform (SGPR)
        unsigned long long bm[8];
#pragma unroll
        for (int j = 0; j < 4; ++j) {
#pragma unroll
            for (int k = 0; k < 2; ++k) {
                float f = md2[j][k];
                unsigned int v; __builtin_memcpy(&v, &f, 4);
                bm[j * 2 + k] = __ballot(v == Mw);
            }
        }
        // first nonzero slot (ascending) + lowest lane = smallest index among
        // ties; pure SALU select chain (uniform values)
        int off = 0; unsigned long long sel = 0;
#pragma unroll
        for (int s = 7; s >= 0; --s)
            if (bm[s] != 0ull) { sel = bm[s]; off = s; }
        int bi = off * 512 + wid * 64 + (int)__builtin_ctzll(sel);
        unsigned long long key =
            ((unsigned long long)Mw << 32) | (unsigned int)~bi;
        if (lane == 0) red[t & 1][wid] = key;   // key is wave-uniform
        __syncthreads();
        TREE8(red, cur)
    }
    __syncthreads();
    // coalesced epilogue: gather centers from LDS, store once
    for (int t = tid; t < NPOINT_; t += 512) {
        int ix = sidx[t];
        out0[(size_t)b * 3 * NPOINT_ + t]               = sx[ix];
        out0[(size_t)b * 3 * NPOINT_ + NPOINT_ + t]     = sy[ix];
        out0[(size_t)b * 3 * NPOINT_ + 2 * NPOINT_ + t] = sz[ix];
    }
}

// ---------- ball query: fp32 FMA-contracted (VERIFIED R10) ----------
__global__ __launch_bounds__(256) void ball_kernel(const float* __restrict__ xyz,
                                                   const float* __restrict__ out0,
                                                   int* __restrict__ ball_idx) {
    int gid  = (blockIdx.x * 256 + threadIdx.x) >> 6;
    int lane = threadIdx.x & 63;
    int b = gid >> 10, s = gid & 1023;
    const float* xb = xyz + (size_t)b * 3 * N_;
    float qx = out0[(size_t)b * 3 * NPOINT_ + s];
    float qy = out0[(size_t)b * 3 * NPOINT_ + NPOINT_ + s];
    float qz = out0[(size_t)b * 3 * NPOINT_ + 2 * NPOINT_ + s];
    float qs = __builtin_fmaf(qz, qz, __builtin_fmaf(qy, qy, __fmul_rn(qx, qx)));
    int cnt = 0, first = 0;
    int* outp = ball_idx + (size_t)gid * NSAMPLE_;
    for (int n0 = 0; n0 < N_; n0 += 64) {
        int n = n0 + lane;
        float px = xb[n], py = xb[N_ + n], pz = xb[2 * N_ + n];
        float dot = __builtin_fmaf(qz, pz, __builtin_fmaf(qy, py, __fmul_rn(qx, px)));
        float ps  = __builtin_fmaf(pz, pz, __builtin_fmaf(py, py, __fmul_rn(px, px)));
        float d   = __fadd_rn(__builtin_fmaf(-2.f, dot, qs), ps);
        bool ok = !(d > 0.04f);
        unsigned long long m = __ballot(ok);
        if (m) {
            if (cnt == 0) first = n0 + (__ffsll((unsigned long long)m) - 1);
            if (ok) {
                int r = __popcll(m & ((1ull << lane) - 1ull));
                int pos = cnt + r;
                if (pos < NSAMPLE_) outp[pos] = n;
            }
            cnt += __popcll(m);
            if (cnt >= NSAMPLE_) break;
        }
    }
    if (cnt < NSAMPLE_) {
        for (int pos = cnt + lane; pos < NSAMPLE_; pos += 64) outp[pos] = first;
    }
}

// ---------- conv1 stats: per-block partial sums of y1, y1^2 ----------
__global__ __launch_bounds__(256) void conv1_stats_kernel(const float* __restrict__ xyz,
                                                          const float* __restrict__ pts,
                                                          const float* __restrict__ out0,
                                                          const int* __restrict__ ball_idx,
                                                          const float* __restrict__ w0,
                                                          const float* __restrict__ b0,
                                                          float* __restrict__ partial1) {
    __shared__ float sw[448];
    __shared__ float lsum[256], lsq[256];
    int tid = threadIdx.x;
    int lane = tid & 63, wid = tid >> 6;
    for (int i = tid; i < 448; i += 256) sw[i] = (i < 384) ? w0[i] : b0[i - 384];
    __syncthreads();
    int p = blockIdx.x * 256 + tid;
    int b = p >> 15, s = (p & 32767) >> 5;
    int gi = ball_idx[p];
    const float* xb = xyz + (size_t)b * 3 * N_;
    const float* pb = pts + (size_t)b * 3 * N_;
    float x0 = xb[gi]          - out0[(size_t)b * 3 * NPOINT_ + s];
    float x1 = xb[N_ + gi]     - out0[(size_t)b * 3 * NPOINT_ + NPOINT_ + s];
    float x2 = xb[2 * N_ + gi] - out0[(size_t)b * 3 * NPOINT_ + 2 * NPOINT_ + s];
    float x3 = pb[gi], x4 = pb[N_ + gi], x5 = pb[2 * N_ + gi];
#pragma unroll
    for (int o = 0; o < 64; ++o) {
        float a = sw[384 + o];
        a += sw[o * 6 + 0] * x0; a += sw[o * 6 + 1] * x1; a += sw[o * 6 + 2] * x2;
        a += sw[o * 6 + 3] * x3; a += sw[o * 6 + 4] * x4; a += sw[o * 6 + 5] * x5;
        float v = a, v2 = a * a;
#pragma unroll
        for (int off = 32; off >= 1; off >>= 1) {
            v  += __shfl_down(v, off);
            v2 += __shfl_down(v2, off);
        }
        if (lane == 0) { lsum[wid * 64 + o] = v; lsq[wid * 64 + o] = v2; }
    }
    __syncthreads();
    if (tid < 64)
        partial1[(size_t)blockIdx.x * 128 + tid] =
            lsum[tid] + lsum[64 + tid] + lsum[128 + tid] + lsum[192 + tid];
    else if (tid < 128) {
        int c = tid - 64;
        partial1[(size_t)blockIdx.x * 128 + tid] =
            lsq[c] + lsq[64 + c] + lsq[128 + c] + lsq[192 + c];
    }
}

// ---------- reduce partials -> scale/shift ----------
__global__ __launch_bounds__(256) void reduce_finalize_kernel(const float* __restrict__ partials,
                                                              int nblocks,
                                                              const float* __restrict__ gamma,
                                                              const float* __restrict__ beta,
                                                              float* __restrict__ scale,
                                                              float* __restrict__ shift) {
    int c = blockIdx.x;
    int tid = threadIdx.x, lane = tid & 63, wid = tid >> 6;
    float s1 = 0.f, s2 = 0.f;
    for (int i = tid; i < nblocks; i += 256) {
        s1 += partials[(size_t)i * 128 + c];
        s2 += partials[(size_t)i * 128 + 64 + c];
    }
#pragma unroll
    for (int off = 32; off >= 1; off >>= 1) {
        s1 += __shfl_down(s1, off);
        s2 += __shfl_down(s2, off);
    }
    __shared__ float r1[4], r2[4];
    if (lane == 0) { r1[wid] = s1; r2[wid] = s2; }
    __syncthreads();
    if (tid == 0) {
        float S1 = r1[0] + r1[1] + r1[2] + r1[3];
        float S2 = r2[0] + r2[1] + r2[2] + r2[3];
        const float inv = 1.f / (float)PTOT;
        float m = S1 * inv;
        float v = S2 * inv - m * m;
        float sc = gamma[c] / sqrtf(v + EPS_);
        scale[c] = sc;
        shift[c] = beta[c] - m * sc;
    }
}

// ---------- conv2 fused: recompute conv1+bn1+relu, 64x64 GEMM, stats, store y2 bf16 ----------
__global__ __launch_bounds__(256) void conv2_fused_kernel(const float* __restrict__ xyz,
                                                          const float* __restrict__ pts,
                                                          const float* __restrict__ out0,
                                                          const int* __restrict__ ball_idx,
                                                          const float* __restrict__ w0,
                                                          const float* __restrict__ b0,
                                                          const float* __restrict__ w1t,  // [64c][64o]
                                                          const float* __restrict__ b1,
                                                          const float* __restrict__ scale1,
                                                          const float* __restrict__ shift1,
                                                          unsigned short* __restrict__ y2,
                                                          float* __restrict__ partial2) {
    __shared__ float sw0[448];
    __shared__ float x1s[6 * 64];
    __shared__ float Xs[64 * 64];
    __shared__ float Ws[64 * 64];
    __shared__ float ssc[64], ssh[64], sb1[64];
    __shared__ float lsum[64], lsq[64];
    int tid = threadIdx.x;
    int p0 = blockIdx.x * 64;
    for (int i = tid; i < 448; i += 256) sw0[i] = (i < 384) ? w0[i] : b0[i - 384];
    for (int i = tid; i < 4096; i += 256) Ws[i] = w1t[i];
    if (tid < 64) { ssc[tid] = scale1[tid]; ssh[tid] = shift1[tid]; sb1[tid] = b1[tid]; }
    if (tid < 64) {
        int p = p0 + tid;
        int b = p >> 15, s = (p & 32767) >> 5;
        int gi = ball_idx[p];
        const float* xb = xyz + (size_t)b * 3 * N_;
        const float* pb = pts + (size_t)b * 3 * N_;
        x1s[0 * 64 + tid] = xb[gi]          - out0[(size_t)b * 3 * NPOINT_ + s];
        x1s[1 * 64 + tid] = xb[N_ + gi]     - out0[(size_t)b * 3 * NPOINT_ + NPOINT_ + s];
        x1s[2 * 64 + tid] = xb[2 * N_ + gi] - out0[(size_t)b * 3 * NPOINT_ + 2 * NPOINT_ + s];
        x1s[3 * 64 + tid] = pb[gi];
        x1s[4 * 64 + tid] = pb[N_ + gi];
        x1s[5 * 64 + tid] = pb[2 * N_ + gi];
    }
    __syncthreads();
    for (int i = tid; i < 4096; i += 256) {
        int c = i >> 6, p = i & 63;
        float a = sw0[384 + c];
        a += sw0[c * 6 + 0] * x1s[p];
        a += sw0[c * 6 + 1] * x1s[64 + p];
        a += sw0[c * 6 + 2] * x1s[128 + p];
        a += sw0[c * 6 + 3] * x1s[192 + p];
        a += sw0[c * 6 + 4] * x1s[256 + p];
        a += sw0[c * 6 + 5] * x1s[320 + p];
        Xs[i] = fmaxf(a * ssc[c] + ssh[c], 0.f);
    }
    __syncthreads();
    int pt = tid & 15, ot = tid >> 4;
    float acc[16];
#pragma unroll
    for (int i = 0; i < 4; ++i) {
        float bv = sb1[ot * 4 + i];
        acc[i * 4 + 0] = bv; acc[i * 4 + 1] = bv; acc[i * 4 + 2] = bv; acc[i * 4 + 3] = bv;
    }
#pragma unroll 4
    for (int c = 0; c < 64; ++c) {
        float4 xv = *(const float4*)&Xs[c * 64 + pt * 4];
        float4 wv = *(const float4*)&Ws[c * 64 + ot * 4];
        acc[0]  += wv.x * xv.x; acc[1]  += wv.x * xv.y; acc[2]  += wv.x * xv.z; acc[3]  += wv.x * xv.w;
        acc[4]  += wv.y * xv.x; acc[5]  += wv.y * xv.y; acc[6]  += wv.y * xv.z; acc[7]  += wv.y * xv.w;
        acc[8]  += wv.z * xv.x; acc[9]  += wv.z * xv.y; acc[10] += wv.z * xv.z; acc[11] += wv.z * xv.w;
        acc[12] += wv.w * xv.x; acc[13] += wv.w * xv.y; acc[14] += wv.w * xv.z; acc[15] += wv.w * xv.w;
    }
    float sA[4], sQ[4];
#pragma unroll
    for (int i = 0; i < 4; ++i) {
        int o = ot * 4 + i;
        ushort4 u;
        u.x = f2bf(acc[i * 4 + 0]); u.y = f2bf(acc[i * 4 + 1]);
        u.z = f2bf(acc[i * 4 + 2]); u.w = f2bf(acc[i * 4 + 3]);
        *(ushort4*)(y2 + (size_t)o * PTOT + p0 + pt * 4) = u;
        sA[i] = acc[i * 4] + acc[i * 4 + 1] + acc[i * 4 + 2] + acc[i * 4 + 3];
        sQ[i] = acc[i * 4] * acc[i * 4] + acc[i * 4 + 1] * acc[i * 4 + 1]
              + acc[i * 4 + 2] * acc[i * 4 + 2] + acc[i * 4 + 3] * acc[i * 4 + 3];
    }
#pragma unroll
    for (int off = 8; off >= 1; off >>= 1) {
#pragma unroll
        for (int i = 0; i < 4; ++i) {
            sA[i] += __shfl_down(sA[i], off);
            sQ[i] += __shfl_down(sQ[i], off);
        }
    }
    if ((tid & 15) == 0) {
#pragma unroll
        for (int i = 0; i < 4; ++i) { lsum[ot * 4 + i] = sA[i]; lsq[ot * 4 + i] = sQ[i]; }
    }
    __syncthreads();
    if (tid < 64) partial2[(size_t)blockIdx.x * 128 + tid] = lsum[tid];
    else if (tid < 128) partial2[(size_t)blockIdx.x * 128 + tid] = lsq[tid - 64];
}

// ---------- gram3: G3 = sum x3 x3^T, s3 = sum x3, x3 = relu(affine2(y2)) ----------
__global__ __launch_bounds__(256) void gram3_kernel(const unsigned short* __restrict__ y2,
                                                    const float* __restrict__ scale2,
                                                    const float* __restrict__ shift2,
                                                    float* __restrict__ G3,
                                                    float* __restrict__ s3) {
    __shared__ __align__(16) float Xst[64 * 68];   // [p][c], stride 68
    __shared__ float ssc[64], ssh[64];
    int tid = threadIdx.x;
    if (tid < 64) { ssc[tid] = scale2[tid]; ssh[tid] = shift2[tid]; }
    int r = tid >> 4, q = tid & 15;
    float g[16];
#pragma unroll
    for (int i = 0; i < 16; ++i) g[i] = 0.f;
    float srow[4] = {0.f, 0.f, 0.f, 0.f};
    int pbase = blockIdx.x * 2048;
    for (int tile = 0; tile < 32; ++tile) {
        __syncthreads();
        int pb = pbase + tile * 64;
        for (int i = tid * 4; i < 4096; i += 1024) {
            int c = i >> 6, p4 = i & 63;
            ushort4 u = *(const ushort4*)(y2 + (size_t)c * PTOT + pb + p4);
            float sc = ssc[c], sh = ssh[c];
            Xst[(p4 + 0) * 68 + c] = fmaxf(bf2f(u.x) * sc + sh, 0.f);
            Xst[(p4 + 1) * 68 + c] = fmaxf(bf2f(u.y) * sc + sh, 0.f);
            Xst[(p4 + 2) * 68 + c] = fmaxf(bf2f(u.z) * sc + sh, 0.f);
            Xst[(p4 + 3) * 68 + c] = fmaxf(bf2f(u.w) * sc + sh, 0.f);
        }
        __syncthreads();
#pragma unroll 4
        for (int p = 0; p < 64; ++p) {
            float4 av = *(const float4*)&Xst[p * 68 + r * 4];
            float4 bv = *(const float4*)&Xst[p * 68 + q * 4];
            g[0]  += av.x * bv.x; g[1]  += av.x * bv.y; g[2]  += av.x * bv.z; g[3]  += av.x * bv.w;
            g[4]  += av.y * bv.x; g[5]  += av.y * bv.y; g[6]  += av.y * bv.z; g[7]  += av.y * bv.w;
            g[8]  += av.z * bv.x; g[9]  += av.z * bv.y; g[10] += av.z * bv.z; g[11] += av.z * bv.w;
            g[12] += av.w * bv.x; g[13] += av.w * bv.y; g[14] += av.w * bv.z; g[15] += av.w * bv.w;
            if (q == 0) { srow[0] += av.x; srow[1] += av.y; srow[2] += av.z; srow[3] += av.w; }
        }
    }
#pragma unroll
    for (int i = 0; i < 4; ++i)
#pragma unroll
        for (int j = 0; j < 4; ++j)
            atomicAdd(&G3[(r * 4 + i) * 64 + q * 4 + j], g[i * 4 + j]);
    if (q == 0) {
#pragma unroll
        for (int i = 0; i < 4; ++i) atomicAdd(&s3[r * 4 + i], srow[i]);
    }
}

// ---------- finalize3: Gram -> scale3/shift3 ----------
__global__ __launch_bounds__(64) void finalize3_kernel(const float* __restrict__ G3,
                                                       const float* __restrict__ s3,
                                                       const float* __restrict__ w2,
                                                       const float* __restrict__ b2,
                                                       const float* __restrict__ gamma,
                                                       const float* __restrict__ beta,
                                                       float* __restrict__ scale,
                                                       float* __restrict__ shift) {
    int o = blockIdx.x * 64 + threadIdx.x;
    const float* wr = w2 + o * 64;
    double ws = 0.0;
    for (int c = 0; c < 64; ++c) ws += (double)wr[c] * (double)s3[c];
    double qf = 0.0;
    for (int i = 0; i < 64; ++i) {
        double ti = 0.0;
        for (int j = 0; j < 64; ++j) ti += (double)G3[i * 64 + j] * (double)wr[j];
        qf += (double)wr[i] * ti;
    }
    const double invP = 1.0 / (double)PTOT;
    double bb = (double)b2[o];
    double mean = ws * invP + bb;
    double ey2 = qf * invP + 2.0 * bb * (ws * invP) + bb * bb;
    double var = ey2 - mean * mean;
    float sc = gamma[o] / sqrtf((float)var + EPS_);
    scale[o] = sc;
    shift[o] = beta[o] - (float)mean * sc;
}

// ---------- conv3 + bn3 + relu + maxpool fused (tiled, bf16 y2 in) ----------
__global__ __launch_bounds__(256) void conv3_maxpool_kernel(const unsigned short* __restrict__ y2,
                                                            const float* __restrict__ w2t,  // [64c][128o]
                                                            const float* __restrict__ b2,
                                                            const float* __restrict__ scale2,
                                                            const float* __restrict__ shift2,
                                                            const float* __restrict__ scale3,
                                                            const float* __restrict__ shift3,
                                                            float* __restrict__ out1) {
    __shared__ float Xs[64 * 64];
    __shared__ float Ws[64 * 128];
    __shared__ float ssc2[64], ssh2[64];
    __shared__ float sb2[128], ssc3[128], ssh3[128];
    __shared__ float gmax[256];   // [2 groups][128 ch]
    int tid = threadIdx.x;
    int p0 = blockIdx.x * 64;
    if (tid < 64) { ssc2[tid] = scale2[tid]; ssh2[tid] = shift2[tid]; }
    for (int i = tid; i < 128; i += 256) { sb2[i] = b2[i]; ssc3[i] = scale3[i]; ssh3[i] = shift3[i]; }
    for (int i = tid; i < 8192; i += 256) Ws[i] = w2t[i];
    __syncthreads();
    for (int i = tid * 4; i < 4096; i += 1024) {
        int c = i >> 6, pp = i & 63;
        ushort4 u = *(const ushort4*)(y2 + (size_t)c * PTOT + p0 + pp);
        float sc = ssc2[c], sh = ssh2[c];
        float4 x;
        x.x = fmaxf(bf2f(u.x) * sc + sh, 0.f);
        x.y = fmaxf(bf2f(u.y) * sc + sh, 0.f);
        x.z = fmaxf(bf2f(u.z) * sc + sh, 0.f);
        x.w = fmaxf(bf2f(u.w) * sc + sh, 0.f);
        *(float4*)&Xs[i] = x;
    }
    int pt = tid & 15, ot = tid >> 4;
    float acc[32];
#pragma unroll
    for (int i = 0; i < 8; ++i) {
        float bv = sb2[ot * 8 + i];
        acc[i * 4 + 0] = bv; acc[i * 4 + 1] = bv; acc[i * 4 + 2] = bv; acc[i * 4 + 3] = bv;
    }
    __syncthreads();
#pragma unroll 4
    for (int c = 0; c < 64; ++c) {
        float4 xv = *(const float4*)&Xs[c * 64 + pt * 4];
#pragma unroll
        for (int i2 = 0; i2 < 2; ++i2) {
            float4 wv = *(const float4*)&Ws[c * 128 + ot * 8 + i2 * 4];
            float* a = &acc[i2 * 16];
            a[0]  += wv.x * xv.x; a[1]  += wv.x * xv.y; a[2]  += wv.x * xv.z; a[3]  += wv.x * xv.w;
            a[4]  += wv.y * xv.x; a[5]  += wv.y * xv.y; a[6]  += wv.y * xv.z; a[7]  += wv.y * xv.w;
            a[8]  += wv.z * xv.x; a[9]  += wv.z * xv.y; a[10] += wv.z * xv.z; a[11] += wv.z * xv.w;
            a[12] += wv.w * xv.x; a[13] += wv.w * xv.y; a[14] += wv.w * xv.z; a[15] += wv.w * xv.w;
        }
    }
    float mx[8];
#pragma unroll
    for (int i = 0; i < 8; ++i) {
        int o = ot * 8 + i;
        float sc = ssc3[o], sh = ssh3[o];
        float m = acc[i * 4 + 0] * sc + sh;
        m = fmaxf(m, acc[i * 4 + 1] * sc + sh);
        m = fmaxf(m, acc[i * 4 + 2] * sc + sh);
        m = fmaxf(m, acc[i * 4 + 3] * sc + sh);
        mx[i] = m;
    }
#pragma unroll
    for (int off = 4; off >= 1; off >>= 1)
#pragma unroll
        for (int i = 0; i < 8; ++i) mx[i] = fmaxf(mx[i], __shfl_down(mx[i], off));
    if ((pt & 7) == 0) {
        int gph = pt >> 3;
#pragma unroll
        for (int i = 0; i < 8; ++i) gmax[gph * 128 + ot * 8 + i] = fmaxf(mx[i], 0.f);
    }
    __syncthreads();
    int b = p0 >> 15, s0 = (p0 & 32767) >> 5;
    int o = tid >> 1, gph = tid & 1;
    out1[(size_t)b * 131072 + (size_t)o * 1024 + s0 + gph] = gmax[gph * 128 + o];
}

extern "C" void kernel_launch(void* const* d_in, const int* in_sizes, int n_in,
                              void* d_out, int out_size, void* d_ws, size_t ws_size,
                              hipStream_t stream) {
    (void)in_sizes; (void)n_in; (void)out_size; (void)ws_size;
    const float* xyz    = (const float*)d_in[0];
    const float* pts    = (const float*)d_in[1];
    const float* w0     = (const float*)d_in[2];
    const float* b0     = (const float*)d_in[3];
    const float* gamma0 = (const float*)d_in[4];
    const float* beta0  = (const float*)d_in[5];
    const float* w1     = (const float*)d_in[6];
    const float* b1     = (const float*)d_in[7];
    const float* gamma1 = (const float*)d_in[8];
    const float* beta1  = (const float*)d_in[9];
    const float* w2     = (const float*)d_in[10];
    const float* b2     = (const float*)d_in[11];
    const float* gamma2 = (const float*)d_in[12];
    const float* beta2  = (const float*)d_in[13];

    char* ws = (char*)d_ws;
    int*   ball_idx = (int*)(ws + 0);                       // 2 MB
    float* partial1 = (float*)(ws + 2097152);               // 1 MB (2048*128)
    float* partial2 = (float*)(ws + 3145728);               // 4 MB (8192*128)
    float* G3       = (float*)(ws + 7340032);               // 16 KB (+ s3 contiguous)
    float* s3       = (float*)(ws + 7356416);               // 256 B
    float* scsh     = (float*)(ws + 7357440);               // 2 KB
    float* w1t      = (float*)(ws + 7359488);               // 16 KB
    float* w2t      = (float*)(ws + 7375872);               // 32 KB
    unsigned short* y2 = (unsigned short*)(ws + 7408640);   // 64 MB -> total ~71.5 MB

    float* scale1 = scsh,       *shift1 = scsh + 64;
    float* scale2 = scsh + 128, *shift2 = scsh + 192;
    float* scale3 = scsh + 256, *shift3 = scsh + 384;

    float* out0 = (float*)d_out;                 // (B,3,NPOINT)
    float* out1 = out0 + B_ * 3 * NPOINT_;       // (B,128,NPOINT)

    hipLaunchKernelGGL(prep_kernel, dim3(32), dim3(256), 0, stream, w1, w2, w1t, w2t, G3);
    hipLaunchKernelGGL(fps_kernel, dim3(B_), dim3(512), 0, stream, xyz, out0);
    hipLaunchKernelGGL(ball_kernel, dim3(4096), dim3(256), 0, stream, xyz, out0, ball_idx);
    hipLaunchKernelGGL(conv1_stats_kernel, dim3(2048), dim3(256), 0, stream,
                       xyz, pts, out0, ball_idx, w0, b0, partial1);
    hipLaunchKernelGGL(reduce_finalize_kernel, dim3(64), dim3(256), 0, stream,
                       partial1, 2048, gamma0, beta0, scale1, shift1);
    hipLaunchKernelGGL(conv2_fused_kernel, dim3(8192), dim3(256), 0, stream,
                       xyz, pts, out0, ball_idx, w0, b0, w1t, b1, scale1, shift1, y2, partial2);
    hipLaunchKernelGGL(reduce_finalize_kernel, dim3(64), dim3(256), 0, stream,
                       partial2, 8192, gamma1, beta1, scale2, shift2);
    hipLaunchKernelGGL(gram3_kernel, dim3(256), dim3(256), 0, stream, y2, scale2, shift2, G3, s3);
    hipLaunchKernelGGL(finalize3_kernel, dim3(2), dim3(64), 0, stream,
                       G3, s3, w2, b2, gamma2, beta2, scale3, shift3);
    hipLaunchKernelGGL(conv3_maxpool_kernel, dim3(8192), dim3(256), 0, stream,
                       y2, w2t, b2, scale2, shift2, scale3, shift3, out1);
}

// Round 6
// 1296.461 us; speedup vs baseline: 1.4532x; 1.0070x over previous
//
#include <hip/hip_runtime.h>
#include <stdint.h>

#define B_ 16
#define N_ 4096
#define NPOINT_ 1024
#define NSAMPLE_ 32
#define PPB 32768            // NPOINT_*NSAMPLE_
#define PTOT 524288          // B_*PPB
#define EPS_ 1e-5f

typedef float v2f __attribute__((ext_vector_type(2)));

// ---------- bf16 helpers ----------
__device__ __forceinline__ float bf2f(unsigned short h) {
    unsigned int u = ((unsigned int)h) << 16;
    float f; __builtin_memcpy(&f, &u, 4); return f;
}
__device__ __forceinline__ unsigned short f2bf(float f) {
    unsigned int u; __builtin_memcpy(&u, &f, 4);
    u = (u + 0x7fffu + ((u >> 16) & 1u)) >> 16;   // RNE
    return (unsigned short)u;
}

// ---------- prep: zero G3/s3, transpose w1,w2 ----------
__global__ __launch_bounds__(256) void prep_kernel(const float* __restrict__ w1,
                                                   const float* __restrict__ w2,
                                                   float* __restrict__ w1t,
                                                   float* __restrict__ w2t,
                                                   float* __restrict__ g3s3) {
    int i = blockIdx.x * 256 + threadIdx.x;   // 32 blocks -> 8192
    if (i < 4160) g3s3[i] = 0.f;
    if (i < 4096) { int o = i >> 6, c = i & 63; w1t[c * 64 + o] = w1[i]; }
    if (i < 8192) { int o = i >> 6, c = i & 63; w2t[c * 128 + o] = w2[i]; }
}

// ---------- FPS (R19 version — at its structural floor ~575 ns/iter) ----------
#define DPP_U32_MAX(ctrl)                                                          \
    {                                                                              \
        unsigned int n = (unsigned int)__builtin_amdgcn_update_dpp(                \
            (int)mb, (int)mb, ctrl, 0xF, 0xF, false);                              \
        mb = (n > mb) ? n : mb;                                                    \
    }

// max tree over 8 per-wave keys; ties across waves resolved by ~idx low word
#define TREE8(RED, CUR)                                                            \
    {                                                                              \
        const ulonglong2* rp = (const ulonglong2*)&RED[t & 1][0];                  \
        ulonglong2 r0 = rp[0], r1 = rp[1], r2 = rp[2], r3 = rp[3];                 \
        unsigned long long a0 = (r0.x > r0.y) ? r0.x : r0.y;                       \
        unsigned long long a1 = (r1.x > r1.y) ? r1.x : r1.y;                       \
        unsigned long long a2 = (r2.x > r2.y) ? r2.x : r2.y;                       \
        unsigned long long a3 = (r3.x > r3.y) ? r3.x : r3.y;                       \
        unsigned long long b0 = (a0 > a1) ? a0 : a1;                               \
        unsigned long long b1 = (a2 > a3) ? a2 : a3;                               \
        unsigned long long mm = (b0 > b1) ? b0 : b1;                               \
        CUR = (int)(~(unsigned int)mm) & (N_ - 1);                                 \
    }

__global__ __launch_bounds__(512) void fps_kernel(const float* __restrict__ xyz,
                                                  float* __restrict__ out0) {
    const int b = blockIdx.x;
    const int tid = threadIdx.x;
    const int lane = tid & 63, wid = tid >> 6;   // wid 0..7
    __shared__ float sx[N_], sy[N_], sz[N_];
    __shared__ __align__(16) unsigned long long red[2][8];
    __shared__ int sidx[NPOINT_];
    const float* xb = xyz + (size_t)b * 3 * N_;
    for (int p = tid; p < N_; p += 512) {
        sx[p] = xb[p]; sy[p] = xb[N_ + p]; sz[p] = xb[2 * N_ + p];
    }
    __syncthreads();
    // slot s = j*2+k covers point index tid + s*512 (ascending in s)
    v2f px2[4], py2[4], pz2[4], md2[4];
#pragma unroll
    for (int j = 0; j < 4; ++j) {
        int p = tid + j * 1024;
        px2[j][0] = sx[p];       px2[j][1] = sx[p + 512];
        py2[j][0] = sy[p];       py2[j][1] = sy[p + 512];
        pz2[j][0] = sz[p];       pz2[j][1] = sz[p + 512];
        md2[j][0] = 1e10f;       md2[j][1] = 1e10f;
    }
    int cur = 0;
    for (int t = 0; t < NPOINT_; ++t) {
        if (tid == 0) sidx[t] = cur;           // LDS only — no vmcnt on the loop
        float cx = sx[cur], cy = sy[cur], cz = sz[cur];
        v2f c2x; c2x[0] = cx; c2x[1] = cx;
        v2f c2y; c2y[0] = cy; c2y[1] = cy;
        v2f c2z; c2z[0] = cz; c2z[1] = cz;
#pragma unroll
        for (int j = 0; j < 4; ++j) {
            // pk sub/mul/fma/min: per-element rounding identical to the
            // scalar __fmul_rn/__builtin_fmaf chain -> same selection
            v2f dx = px2[j] - c2x;
            v2f dy = py2[j] - c2y;
            v2f dz = pz2[j] - c2z;
            v2f t0 = dx * dx;
            v2f t1 = __builtin_elementwise_fma(dy, dy, t0);
            v2f d2 = __builtin_elementwise_fma(dz, dz, t1);
            md2[j] = __builtin_elementwise_min(md2[j], d2);
        }
        // lane-local max of the 8 running minima (value only)
        v2f m01 = __builtin_elementwise_max(md2[0], md2[1]);
        v2f m23 = __builtin_elementwise_max(md2[2], md2[3]);
        v2f mq  = __builtin_elementwise_max(m01, m23);
        float lm = fmaxf(mq[0], mq[1]);
        unsigned int mb; __builtin_memcpy(&mb, &lm, 4);   // >=0 -> monotone bits
        DPP_U32_MAX(0x111)   // row_shr:1
        DPP_U32_MAX(0x112)   // row_shr:2
        DPP_U32_MAX(0x114)   // row_shr:4
        DPP_U32_MAX(0x118)   // row_shr:8
        DPP_U32_MAX(0x142)   // row_bcast:15
        DPP_U32_MAX(0x143)   // row_bcast:31
        unsigned int Mw = (unsigned int)__builtin_amdgcn_readlane((int)mb, 63);
        // equality ballots in slot order; results are wave-uniform (SGPR)
        unsigned long long bm[8];
#pragma unroll
        for (int j = 0; j < 4; ++j) {
#pragma unroll
            for (int k = 0; k < 2; ++k) {
                float f = md2[j][k];
                unsigned int v; __builtin_memcpy(&v, &f, 4);
                bm[j * 2 + k] = __ballot(v == Mw);
            }
        }
        // first nonzero slot (ascending) + lowest lane = smallest index among
        // ties; pure SALU select chain (uniform values)
        int off = 0; unsigned long long sel = 0;
#pragma unroll
        for (int s = 7; s >= 0; --s)
            if (bm[s] != 0ull) { sel = bm[s]; off = s; }
        int bi = off * 512 + wid * 64 + (int)__builtin_ctzll(sel);
        unsigned long long key =
            ((unsigned long long)Mw << 32) | (unsigned int)~bi;
        if (lane == 0) red[t & 1][wid] = key;   // key is wave-uniform
        __syncthreads();
        TREE8(red, cur)
    }
    __syncthreads();
    // coalesced epilogue: gather centers from LDS, store once
    for (int t = tid; t < NPOINT_; t += 512) {
        int ix = sidx[t];
        out0[(size_t)b * 3 * NPOINT_ + t]               = sx[ix];
        out0[(size_t)b * 3 * NPOINT_ + NPOINT_ + t]     = sy[ix];
        out0[(size_t)b * 3 * NPOINT_ + 2 * NPOINT_ + t] = sz[ix];
    }
}

// ---------- ball query: fp32 FMA-contracted (VERIFIED R10) ----------
// R20: removed the early 'break' — with N(0,1) data the expected in-radius
// count (~3) almost never reaches 32, so the break rarely fired but blocked
// load pipelining across iterations. Outputs identical (pos guard handles
// cnt past NSAMPLE_; 'first' logic unchanged).
__global__ __launch_bounds__(256) void ball_kernel(const float* __restrict__ xyz,
                                                   const float* __restrict__ out0,
                                                   int* __restrict__ ball_idx) {
    int gid  = (blockIdx.x * 256 + threadIdx.x) >> 6;
    int lane = threadIdx.x & 63;
    int b = gid >> 10, s = gid & 1023;
    const float* xb = xyz + (size_t)b * 3 * N_;
    float qx = out0[(size_t)b * 3 * NPOINT_ + s];
    float qy = out0[(size_t)b * 3 * NPOINT_ + NPOINT_ + s];
    float qz = out0[(size_t)b * 3 * NPOINT_ + 2 * NPOINT_ + s];
    float qs = __builtin_fmaf(qz, qz, __builtin_fmaf(qy, qy, __fmul_rn(qx, qx)));
    int cnt = 0, first = 0;
    int* outp = ball_idx + (size_t)gid * NSAMPLE_;
#pragma unroll 2
    for (int n0 = 0; n0 < N_; n0 += 64) {
        int n = n0 + lane;
        float px = xb[n], py = xb[N_ + n], pz = xb[2 * N_ + n];
        float dot = __builtin_fmaf(qz, pz, __builtin_fmaf(qy, py, __fmul_rn(qx, px)));
        float ps  = __builtin_fmaf(pz, pz, __builtin_fmaf(py, py, __fmul_rn(px, px)));
        float d   = __fadd_rn(__builtin_fmaf(-2.f, dot, qs), ps);
        bool ok = !(d > 0.04f);
        unsigned long long m = __ballot(ok);
        if (m) {
            if (cnt == 0) first = n0 + (__ffsll((unsigned long long)m) - 1);
            if (ok) {
                int r = __popcll(m & ((1ull << lane) - 1ull));
                int pos = cnt + r;
                if (pos < NSAMPLE_) outp[pos] = n;
            }
            cnt += __popcll(m);
        }
    }
    if (cnt < NSAMPLE_) {
        for (int pos = cnt + lane; pos < NSAMPLE_; pos += 64) outp[pos] = first;
    }
    else if (cnt > NSAMPLE_) { /* outputs already capped by pos guard */ }
}

// ---------- conv1 stats: per-block partial sums of y1, y1^2 ----------
__global__ __launch_bounds__(256) void conv1_stats_kernel(const float* __restrict__ xyz,
                                                          const float* __restrict__ pts,
                                                          const float* __restrict__ out0,
                                                          const int* __restrict__ ball_idx,
                                                          const float* __restrict__ w0,
                                                          const float* __restrict__ b0,
                                                          float* __restrict__ partial1) {
    __shared__ float sw[448];
    __shared__ float lsum[256], lsq[256];
    int tid = threadIdx.x;
    int lane = tid & 63, wid = tid >> 6;
    for (int i = tid; i < 448; i += 256) sw[i] = (i < 384) ? w0[i] : b0[i - 384];
    __syncthreads();
    int p = blockIdx.x * 256 + tid;
    int b = p >> 15, s = (p & 32767) >> 5;
    int gi = ball_idx[p];
    const float* xb = xyz + (size_t)b * 3 * N_;
    const float* pb = pts + (size_t)b * 3 * N_;
    float x0 = xb[gi]          - out0[(size_t)b * 3 * NPOINT_ + s];
    float x1 = xb[N_ + gi]     - out0[(size_t)b * 3 * NPOINT_ + NPOINT_ + s];
    float x2 = xb[2 * N_ + gi] - out0[(size_t)b * 3 * NPOINT_ + 2 * NPOINT_ + s];
    float x3 = pb[gi], x4 = pb[N_ + gi], x5 = pb[2 * N_ + gi];
#pragma unroll
    for (int o = 0; o < 64; ++o) {
        float a = sw[384 + o];
        a += sw[o * 6 + 0] * x0; a += sw[o * 6 + 1] * x1; a += sw[o * 6 + 2] * x2;
        a += sw[o * 6 + 3] * x3; a += sw[o * 6 + 4] * x4; a += sw[o * 6 + 5] * x5;
        float v = a, v2 = a * a;
#pragma unroll
        for (int off = 32; off >= 1; off >>= 1) {
            v  += __shfl_down(v, off);
            v2 += __shfl_down(v2, off);
        }
        if (lane == 0) { lsum[wid * 64 + o] = v; lsq[wid * 64 + o] = v2; }
    }
    __syncthreads();
    if (tid < 64)
        partial1[(size_t)blockIdx.x * 128 + tid] =
            lsum[tid] + lsum[64 + tid] + lsum[128 + tid] + lsum[192 + tid];
    else if (tid < 128) {
        int c = tid - 64;
        partial1[(size_t)blockIdx.x * 128 + tid] =
            lsq[c] + lsq[64 + c] + lsq[128 + c] + lsq[192 + c];
    }
}

// ---------- reduce partials -> scale/shift ----------
__global__ __launch_bounds__(256) void reduce_finalize_kernel(const float* __restrict__ partials,
                                                              int nblocks,
                                                              const float* __restrict__ gamma,
                                                              const float* __restrict__ beta,
                                                              float* __restrict__ scale,
                                                              float* __restrict__ shift) {
    int c = blockIdx.x;
    int tid = threadIdx.x, lane = tid & 63, wid = tid >> 6;
    float s1 = 0.f, s2 = 0.f;
    for (int i = tid; i < nblocks; i += 256) {
        s1 += partials[(size_t)i * 128 + c];
        s2 += partials[(size_t)i * 128 + 64 + c];
    }
#pragma unroll
    for (int off = 32; off >= 1; off >>= 1) {
        s1 += __shfl_down(s1, off);
        s2 += __shfl_down(s2, off);
    }
    __shared__ float r1[4], r2[4];
    if (lane == 0) { r1[wid] = s1; r2[wid] = s2; }
    __syncthreads();
    if (tid == 0) {
        float S1 = r1[0] + r1[1] + r1[2] + r1[3];
        float S2 = r2[0] + r2[1] + r2[2] + r2[3];
        const float inv = 1.f / (float)PTOT;
        float m = S1 * inv;
        float v = S2 * inv - m * m;
        float sc = gamma[c] / sqrtf(v + EPS_);
        scale[c] = sc;
        shift[c] = beta[c] - m * sc;
    }
}

// ---------- conv2 fused: recompute conv1+bn1+relu, 64x64 GEMM, stats, store y2 bf16 ----------
__global__ __launch_bounds__(256) void conv2_fused_kernel(const float* __restrict__ xyz,
                                                          const float* __restrict__ pts,
                                                          const float* __restrict__ out0,
                                                          const int* __restrict__ ball_idx,
                                                          const float* __restrict__ w0,
                                                          const float* __restrict__ b0,
                                                          const float* __restrict__ w1t,  // [64c][64o]
                                                          const float* __restrict__ b1,
                                                          const float* __restrict__ scale1,
                                                          const float* __restrict__ shift1,
                                                          unsigned short* __restrict__ y2,
                                                          float* __restrict__ partial2) {
    __shared__ float sw0[448];
    __shared__ float x1s[6 * 64];
    __shared__ float Xs[64 * 64];
    __shared__ float Ws[64 * 64];
    __shared__ float ssc[64], ssh[64], sb1[64];
    __shared__ float lsum[64], lsq[64];
    int tid = threadIdx.x;
    int p0 = blockIdx.x * 64;
    for (int i = tid; i < 448; i += 256) sw0[i] = (i < 384) ? w0[i] : b0[i - 384];
    for (int i = tid; i < 4096; i += 256) Ws[i] = w1t[i];
    if (tid < 64) { ssc[tid] = scale1[tid]; ssh[tid] = shift1[tid]; sb1[tid] = b1[tid]; }
    if (tid < 64) {
        int p = p0 + tid;
        int b = p >> 15, s = (p & 32767) >> 5;
        int gi = ball_idx[p];
        const float* xb = xyz + (size_t)b * 3 * N_;
        const float* pb = pts + (size_t)b * 3 * N_;
        x1s[0 * 64 + tid] = xb[gi]          - out0[(size_t)b * 3 * NPOINT_ + s];
        x1s[1 * 64 + tid] = xb[N_ + gi]     - out0[(size_t)b * 3 * NPOINT_ + NPOINT_ + s];
        x1s[2 * 64 + tid] = xb[2 * N_ + gi] - out0[(size_t)b * 3 * NPOINT_ + 2 * NPOINT_ + s];
        x1s[3 * 64 + tid] = pb[gi];
        x1s[4 * 64 + tid] = pb[N_ + gi];
        x1s[5 * 64 + tid] = pb[2 * N_ + gi];
    }
    __syncthreads();
    for (int i = tid; i < 4096; i += 256) {
        int c = i >> 6, p = i & 63;
        float a = sw0[384 + c];
        a += sw0[c * 6 + 0] * x1s[p];
        a += sw0[c * 6 + 1] * x1s[64 + p];
        a += sw0[c * 6 + 2] * x1s[128 + p];
        a += sw0[c * 6 + 3] * x1s[192 + p];
        a += sw0[c * 6 + 4] * x1s[256 + p];
        a += sw0[c * 6 + 5] * x1s[320 + p];
        Xs[i] = fmaxf(a * ssc[c] + ssh[c], 0.f);
    }
    __syncthreads();
    int pt = tid & 15, ot = tid >> 4;
    float acc[16];
#pragma unroll
    for (int i = 0; i < 4; ++i) {
        float bv = sb1[ot * 4 + i];
        acc[i * 4 + 0] = bv; acc[i * 4 + 1] = bv; acc[i * 4 + 2] = bv; acc[i * 4 + 3] = bv;
    }
#pragma unroll 4
    for (int c = 0; c < 64; ++c) {
        float4 xv = *(const float4*)&Xs[c * 64 + pt * 4];
        float4 wv = *(const float4*)&Ws[c * 64 + ot * 4];
        acc[0]  += wv.x * xv.x; acc[1]  += wv.x * xv.y; acc[2]  += wv.x * xv.z; acc[3]  += wv.x * xv.w;
        acc[4]  += wv.y * xv.x; acc[5]  += wv.y * xv.y; acc[6]  += wv.y * xv.z; acc[7]  += wv.y * xv.w;
        acc[8]  += wv.z * xv.x; acc[9]  += wv.z * xv.y; acc[10] += wv.z * xv.z; acc[11] += wv.z * xv.w;
        acc[12] += wv.w * xv.x; acc[13] += wv.w * xv.y; acc[14] += wv.w * xv.z; acc[15] += wv.w * xv.w;
    }
    float sA[4], sQ[4];
#pragma unroll
    for (int i = 0; i < 4; ++i) {
        int o = ot * 4 + i;
        ushort4 u;
        u.x = f2bf(acc[i * 4 + 0]); u.y = f2bf(acc[i * 4 + 1]);
        u.z = f2bf(acc[i * 4 + 2]); u.w = f2bf(acc[i * 4 + 3]);
        *(ushort4*)(y2 + (size_t)o * PTOT + p0 + pt * 4) = u;
        sA[i] = acc[i * 4] + acc[i * 4 + 1] + acc[i * 4 + 2] + acc[i * 4 + 3];
        sQ[i] = acc[i * 4] * acc[i * 4] + acc[i * 4 + 1] * acc[i * 4 + 1]
              + acc[i * 4 + 2] * acc[i * 4 + 2] + acc[i * 4 + 3] * acc[i * 4 + 3];
    }
#pragma unroll
    for (int off = 8; off >= 1; off >>= 1) {
#pragma unroll
        for (int i = 0; i < 4; ++i) {
            sA[i] += __shfl_down(sA[i], off);
            sQ[i] += __shfl_down(sQ[i], off);
        }
    }
    if ((tid & 15) == 0) {
#pragma unroll
        for (int i = 0; i < 4; ++i) { lsum[ot * 4 + i] = sA[i]; lsq[ot * 4 + i] = sQ[i]; }
    }
    __syncthreads();
    if (tid < 64) partial2[(size_t)blockIdx.x * 128 + tid] = lsum[tid];
    else if (tid < 128) partial2[(size_t)blockIdx.x * 128 + tid] = lsq[tid - 64];
}

// ---------- gram3: G3 = sum x3 x3^T, s3 = sum x3, x3 = relu(affine2(y2)) ----------
// R20: 256 -> 1024 blocks (8 tiles each, was 32). At 256 blocks this kernel
// ran 1 block/CU = 1 wave/SIMD: the ds_read_b128 -> FMA inner loop had ZERO
// TLP to hide ~120-cyc LDS latency. 1024 blocks -> 4 blocks/CU (17.4 KB LDS
// each) = 16 waves/CU. Accumulation via atomicAdd is block-count-agnostic
// (order already nondeterministic; finalize3 consumes in double).
__global__ __launch_bounds__(256) void gram3_kernel(const unsigned short* __restrict__ y2,
                                                    const float* __restrict__ scale2,
                                                    const float* __restrict__ shift2,
                                                    float* __restrict__ G3,
                                                    float* __restrict__ s3) {
    __shared__ __align__(16) float Xst[64 * 68];   // [p][c], stride 68
    __shared__ float ssc[64], ssh[64];
    int tid = threadIdx.x;
    if (tid < 64) { ssc[tid] = scale2[tid]; ssh[tid] = shift2[tid]; }
    int r = tid >> 4, q = tid & 15;
    float g[16];
#pragma unroll
    for (int i = 0; i < 16; ++i) g[i] = 0.f;
    float srow[4] = {0.f, 0.f, 0.f, 0.f};
    int pbase = blockIdx.x * 512;
    for (int tile = 0; tile < 8; ++tile) {
        __syncthreads();
        int pb = pbase + tile * 64;
        for (int i = tid * 4; i < 4096; i += 1024) {
            int c = i >> 6, p4 = i & 63;
            ushort4 u = *(const ushort4*)(y2 + (size_t)c * PTOT + pb + p4);
            float sc = ssc[c], sh = ssh[c];
            Xst[(p4 + 0) * 68 + c] = fmaxf(bf2f(u.x) * sc + sh, 0.f);
            Xst[(p4 + 1) * 68 + c] = fmaxf(bf2f(u.y) * sc + sh, 0.f);
            Xst[(p4 + 2) * 68 + c] = fmaxf(bf2f(u.z) * sc + sh, 0.f);
            Xst[(p4 + 3) * 68 + c] = fmaxf(bf2f(u.w) * sc + sh, 0.f);
        }
        __syncthreads();
#pragma unroll 4
        for (int p = 0; p < 64; ++p) {
            float4 av = *(const float4*)&Xst[p * 68 + r * 4];
            float4 bv = *(const float4*)&Xst[p * 68 + q * 4];
            g[0]  += av.x * bv.x; g[1]  += av.x * bv.y; g[2]  += av.x * bv.z; g[3]  += av.x * bv.w;
            g[4]  += av.y * bv.x; g[5]  += av.y * bv.y; g[6]  += av.y * bv.z; g[7]  += av.y * bv.w;
            g[8]  += av.z * bv.x; g[9]  += av.z * bv.y; g[10] += av.z * bv.z; g[11] += av.z * bv.w;
            g[12] += av.w * bv.x; g[13] += av.w * bv.y; g[14] += av.w * bv.z; g[15] += av.w * bv.w;
            if (q == 0) { srow[0] += av.x; srow[1] += av.y; srow[2] += av.z; srow[3] += av.w; }
        }
    }
#pragma unroll
    for (int i = 0; i < 4; ++i)
#pragma unroll
        for (int j = 0; j < 4; ++j)
            atomicAdd(&G3[(r * 4 + i) * 64 + q * 4 + j], g[i * 4 + j]);
    if (q == 0) {
#pragma unroll
        for (int i = 0; i < 4; ++i) atomicAdd(&s3[r * 4 + i], srow[i]);
    }
}

// ---------- finalize3: Gram -> scale3/shift3 ----------
__global__ __launch_bounds__(64) void finalize3_kernel(const float* __restrict__ G3,
                                                       const float* __restrict__ s3,
                                                       const float* __restrict__ w2,
                                                       const float* __restrict__ b2,
                                                       const float* __restrict__ gamma,
                                                       const float* __restrict__ beta,
                                                       float* __restrict__ scale,
                                                       float* __restrict__ shift) {
    int o = blockIdx.x * 64 + threadIdx.x;
    const float* wr = w2 + o * 64;
    double ws = 0.0;
    for (int c = 0; c < 64; ++c) ws += (double)wr[c] * (double)s3[c];
    double qf = 0.0;
    for (int i = 0; i < 64; ++i) {
        double ti = 0.0;
        for (int j = 0; j < 64; ++j) ti += (double)G3[i * 64 + j] * (double)wr[j];
        qf += (double)wr[i] * ti;
    }
    const double invP = 1.0 / (double)PTOT;
    double bb = (double)b2[o];
    double mean = ws * invP + bb;
    double ey2 = qf * invP + 2.0 * bb * (ws * invP) + bb * bb;
    double var = ey2 - mean * mean;
    float sc = gamma[o] / sqrtf((float)var + EPS_);
    scale[o] = sc;
    shift[o] = beta[o] - (float)mean * sc;
}

// ---------- conv3 + bn3 + relu + maxpool fused (tiled, bf16 y2 in) ----------
__global__ __launch_bounds__(256) void conv3_maxpool_kernel(const unsigned short* __restrict__ y2,
                                                            const float* __restrict__ w2t,  // [64c][128o]
                                                            const float* __restrict__ b2,
                                                            const float* __restrict__ scale2,
                                                            const float* __restrict__ shift2,
                                                            const float* __restrict__ scale3,
                                                            const float* __restrict__ shift3,
                                                            float* __restrict__ out1) {
    __shared__ float Xs[64 * 64];
    __shared__ float Ws[64 * 128];
    __shared__ float ssc2[64], ssh2[64];
    __shared__ float sb2[128], ssc3[128], ssh3[128];
    __shared__ float gmax[256];   // [2 groups][128 ch]
    int tid = threadIdx.x;
    int p0 = blockIdx.x * 64;
    if (tid < 64) { ssc2[tid] = scale2[tid]; ssh2[tid] = shift2[tid]; }
    for (int i = tid; i < 128; i += 256) { sb2[i] = b2[i]; ssc3[i] = scale3[i]; ssh3[i] = shift3[i]; }
    for (int i = tid; i < 8192; i += 256) Ws[i] = w2t[i];
    __syncthreads();
    for (int i = tid * 4; i < 4096; i += 1024) {
        int c = i >> 6, pp = i & 63;
        ushort4 u = *(const ushort4*)(y2 + (size_t)c * PTOT + p0 + pp);
        float sc = ssc2[c], sh = ssh2[c];
        float4 x;
        x.x = fmaxf(bf2f(u.x) * sc + sh, 0.f);
        x.y = fmaxf(bf2f(u.y) * sc + sh, 0.f);
        x.z = fmaxf(bf2f(u.z) * sc + sh, 0.f);
        x.w = fmaxf(bf2f(u.w) * sc + sh, 0.f);
        *(float4*)&Xs[i] = x;
    }
    int pt = tid & 15, ot = tid >> 4;
    float acc[32];
#pragma unroll
    for (int i = 0; i < 8; ++i) {
        float bv = sb2[ot * 8 + i];
        acc[i * 4 + 0] = bv; acc[i * 4 + 1] = bv; acc[i * 4 + 2] = bv; acc[i * 4 + 3] = bv;
    }
    __syncthreads();
#pragma unroll 4
    for (int c = 0; c < 64; ++c) {
        float4 xv = *(const float4*)&Xs[c * 64 + pt * 4];
#pragma unroll
        for (int i2 = 0; i2 < 2; ++i2) {
            float4 wv = *(const float4*)&Ws[c * 128 + ot * 8 + i2 * 4];
            float* a = &acc[i2 * 16];
            a[0]  += wv.x * xv.x; a[1]  += wv.x * xv.y; a[2]  += wv.x * xv.z; a[3]  += wv.x * xv.w;
            a[4]  += wv.y * xv.x; a[5]  += wv.y * xv.y; a[6]  += wv.y * xv.z; a[7]  += wv.y * xv.w;
            a[8]  += wv.z * xv.x; a[9]  += wv.z * xv.y; a[10] += wv.z * xv.z; a[11] += wv.z * xv.w;
            a[12] += wv.w * xv.x; a[13] += wv.w * xv.y; a[14] += wv.w * xv.z; a[15] += wv.w * xv.w;
        }
    }
    float mx[8];
#pragma unroll
    for (int i = 0; i < 8; ++i) {
        int o = ot * 8 + i;
        float sc = ssc3[o], sh = ssh3[o];
        float m = acc[i * 4 + 0] * sc + sh;
        m = fmaxf(m, acc[i * 4 + 1] * sc + sh);
        m = fmaxf(m, acc[i * 4 + 2] * sc + sh);
        m = fmaxf(m, acc[i * 4 + 3] * sc + sh);
        mx[i] = m;
    }
#pragma unroll
    for (int off = 4; off >= 1; off >>= 1)
#pragma unroll
        for (int i = 0; i < 8; ++i) mx[i] = fmaxf(mx[i], __shfl_down(mx[i], off));
    if ((pt & 7) == 0) {
        int gph = pt >> 3;
#pragma unroll
        for (int i = 0; i < 8; ++i) gmax[gph * 128 + ot * 8 + i] = fmaxf(mx[i], 0.f);
    }
    __syncthreads();
    int b = p0 >> 15, s0 = (p0 & 32767) >> 5;
    int o = tid >> 1, gph = tid & 1;
    out1[(size_t)b * 131072 + (size_t)o * 1024 + s0 + gph] = gmax[gph * 128 + o];
}

extern "C" void kernel_launch(void* const* d_in, const int* in_sizes, int n_in,
                              void* d_out, int out_size, void* d_ws, size_t ws_size,
                              hipStream_t stream) {
    (void)in_sizes; (void)n_in; (void)out_size; (void)ws_size;
    const float* xyz    = (const float*)d_in[0];
    const float* pts    = (const float*)d_in[1];
    const float* w0     = (const float*)d_in[2];
    const float* b0     = (const float*)d_in[3];
    const float* gamma0 = (const float*)d_in[4];
    const float* beta0  = (const float*)d_in[5];
    const float* w1     = (const float*)d_in[6];
    const float* b1     = (const float*)d_in[7];
    const float* gamma1 = (const float*)d_in[8];
    const float* beta1  = (const float*)d_in[9];
    const float* w2     = (const float*)d_in[10];
    const float* b2     = (const float*)d_in[11];
    const float* gamma2 = (const float*)d_in[12];
    const float* beta2  = (const float*)d_in[13];

    char* ws = (char*)d_ws;
    int*   ball_idx = (int*)(ws + 0);                       // 2 MB
    float* partial1 = (float*)(ws + 2097152);               // 1 MB (2048*128)
    float* partial2 = (float*)(ws + 3145728);               // 4 MB (8192*128)
    float* G3       = (float*)(ws + 7340032);               // 16 KB (+ s3 contiguous)
    float* s3       = (float*)(ws + 7356416);               // 256 B
    float* scsh     = (float*)(ws + 7357440);               // 2 KB
    float* w1t      = (float*)(ws + 7359488);               // 16 KB
    float* w2t      = (float*)(ws + 7375872);               // 32 KB
    unsigned short* y2 = (unsigned short*)(ws + 7408640);   // 64 MB -> total ~71.5 MB

    float* scale1 = scsh,       *shift1 = scsh + 64;
    float* scale2 = scsh + 128, *shift2 = scsh + 192;
    float* scale3 = scsh + 256, *shift3 = scsh + 384;

    float* out0 = (float*)d_out;                 // (B,3,NPOINT)
    float* out1 = out0 + B_ * 3 * NPOINT_;       // (B,128,NPOINT)

    hipLaunchKernelGGL(prep_kernel, dim3(32), dim3(256), 0, stream, w1, w2, w1t, w2t, G3);
    hipLaunchKernelGGL(fps_kernel, dim3(B_), dim3(512), 0, stream, xyz, out0);
    hipLaunchKernelGGL(ball_kernel, dim3(4096), dim3(256), 0, stream, xyz, out0, ball_idx);
    hipLaunchKernelGGL(conv1_stats_kernel, dim3(2048), dim3(256), 0, stream,
                       xyz, pts, out0, ball_idx, w0, b0, partial1);
    hipLaunchKernelGGL(reduce_finalize_kernel, dim3(64), dim3(256), 0, stream,
                       partial1, 2048, gamma0, beta0, scale1, shift1);
    hipLaunchKernelGGL(conv2_fused_kernel, dim3(8192), dim3(256), 0, stream,
                       xyz, pts, out0, ball_idx, w0, b0, w1t, b1, scale1, shift1, y2, partial2);
    hipLaunchKernelGGL(reduce_finalize_kernel, dim3(64), dim3(256), 0, stream,
                       partial2, 8192, gamma1, beta1, scale2, shift2);
    hipLaunchKernelGGL(gram3_kernel, dim3(1024), dim3(256), 0, stream, y2, scale2, shift2, G3, s3);
    hipLaunchKernelGGL(finalize3_kernel, dim3(2), dim3(64), 0, stream,
                       G3, s3, w2, b2, gamma2, beta2, scale3, shift3);
    hipLaunchKernelGGL(conv3_maxpool_kernel, dim3(8192), dim3(256), 0, stream,
                       y2, w2t, b2, scale2, shift2, scale3, shift3, out1);
}